// Round 3
// baseline (171.078 us; speedup 1.0000x reference)
//
#include <hip/hip_runtime.h>
#include <hip/hip_bf16.h>

#define V_N   40000
#define P_N   32
#define NTOT  (V_N * P_N)            // BN batch positions
#define VXc   0.16f
#define VYc   0.16f
#define XOFF  0.08f                  // VX/2 + 0.0
#define YOFF  (-39.6f)               // VY/2 - 39.68
#define BN_EPS 1e-5f

#define SBLK  1250                   // stats blocks: 5000 waves x 2 voxels/iter
#define PBLK  2500                   // pfn blocks: 10000 waves x 4 voxels = 40000

// ---------------------------------------------------------------------------
// Kernel 1: S[9] = sum f, M[45] = upper-tri sum f f^T over valid (v,p).
// (v,p)-parallel: each wave handles 2 voxels/iter (lane&31 = point, lane>>5 =
// which voxel). Coalesced 1 KiB/wave loads.
// __launch_bounds__(256, 1): allow up to 512 VGPRs so the 54 accumulators
// stay in registers (default cap spilled them -> 226 MB scratch writes).
// ---------------------------------------------------------------------------
__global__ __launch_bounds__(256, 1) void stats_kernel(
    const float4* __restrict__ voxels,
    const int*    __restrict__ npts_arr,
    const int*    __restrict__ coors,
    float*        __restrict__ stats)       // 54 floats, pre-zeroed
{
    const int lane = threadIdx.x & 63;
    const int p    = lane & 31;
    const int half = lane >> 5;
    const int gw   = (blockIdx.x * 256 + threadIdx.x) >> 6;
    const int nw   = (SBLK * 256) >> 6;

    float S[9], M[45];
#pragma unroll
    for (int i = 0; i < 9; ++i)  S[i] = 0.f;
#pragma unroll
    for (int i = 0; i < 45; ++i) M[i] = 0.f;

    for (int vb = gw * 2; vb < V_N; vb += nw * 2) {
        const int v = vb + half;                       // V_N even -> in range
        float4 q = voxels[(size_t)v * P_N + p];

        // per-voxel xyz sum over ALL 32 points (reference does not mask here)
        float sx = q.x, sy = q.y, sz = q.z;
#pragma unroll
        for (int m = 1; m < 32; m <<= 1) {
            sx += __shfl_xor(sx, m, 64);
            sy += __shfl_xor(sy, m, 64);
            sz += __shfl_xor(sz, m, 64);
        }
        const int   npts = npts_arr[v];
        const float inv  = 1.f / (float)npts;
        const float cx = (float)coors[2 * v]     * VXc + XOFF;
        const float cy = (float)coors[2 * v + 1] * VYc + YOFF;

        if (p < npts) {
            float f[9];
            f[0] = q.x; f[1] = q.y; f[2] = q.z; f[3] = q.w;
            f[4] = q.x - sx * inv; f[5] = q.y - sy * inv; f[6] = q.z - sz * inv;
            f[7] = q.x - cx;       f[8] = q.y - cy;
            int k = 0;
#pragma unroll
            for (int i = 0; i < 9; ++i) {
                S[i] += f[i];
#pragma unroll
                for (int j = i; j < 9; ++j) { M[k] = fmaf(f[i], f[j], M[k]); ++k; }
            }
        }
    }

    // full 64-lane butterfly (sums both halves = both voxel streams)
#pragma unroll
    for (int i = 0; i < 9; ++i)
#pragma unroll
        for (int m = 1; m < 64; m <<= 1) S[i] += __shfl_xor(S[i], m, 64);
#pragma unroll
    for (int i = 0; i < 45; ++i)
#pragma unroll
        for (int m = 1; m < 64; m <<= 1) M[i] += __shfl_xor(M[i], m, 64);

    // block-level reduce (4 waves) then 54 parallel-lane atomics per block
    __shared__ float red[4][54];
    const int wib = threadIdx.x >> 6;
    if (lane == 0) {
#pragma unroll
        for (int i = 0; i < 9;  ++i) red[wib][i]     = S[i];
#pragma unroll
        for (int i = 0; i < 45; ++i) red[wib][9 + i] = M[i];
    }
    __syncthreads();
    if (threadIdx.x < 54) {
        float s = red[0][threadIdx.x] + red[1][threadIdx.x]
                + red[2][threadIdx.x] + red[3][threadIdx.x];
        atomicAdd(&stats[threadIdx.x], s);
    }
}

// ---------------------------------------------------------------------------
// Kernel 2: one wave per voxel iter (4 voxels per wave). Lane o = out channel.
// Folded affine: scale*(f_p . w_o) = q_p . a_o + b_{v,o} with a_o per-lane
// constants (scale folded in) and b point-invariant -> added after the max.
// Inner loop: 1 ds_read_b128 broadcast + 4 FMA + sel/max per point.
// (unchanged this round so its counters surface cleanly)
// ---------------------------------------------------------------------------
__global__ __launch_bounds__(256) void pfn_kernel(
    const float4* __restrict__ voxels,
    const int*    __restrict__ npts_arr,
    const int*    __restrict__ coors,
    const float*  __restrict__ W,        // (64, 9) row-major
    const float*  __restrict__ gamma,
    const float*  __restrict__ beta,
    const float*  __restrict__ stats,    // 54 floats
    float*        __restrict__ out)      // (V, 64)
{
    __shared__ float4 sq[4][P_N];
    const int wib  = threadIdx.x >> 6;
    const int lane = threadIdx.x & 63;
    const int pl   = lane & 31;

    // ---- BN affine from moment statistics (once per wave) ----
    float w[9];
#pragma unroll
    for (int c = 0; c < 9; ++c) w[c] = W[lane * 9 + c];

    const float invN = 1.f / (float)NTOT;
    float mean = 0.f;
#pragma unroll
    for (int c = 0; c < 9; ++c) mean = fmaf(w[c], stats[c], mean);
    mean *= invN;

    float ex2 = 0.f;
    {
        int k = 9;
#pragma unroll
        for (int i = 0; i < 9; ++i)
#pragma unroll
            for (int j = i; j < 9; ++j) {
                const float coef = (i == j) ? 1.f : 2.f;
                ex2 = fmaf(coef * w[i] * w[j], stats[k], ex2);
                ++k;
            }
    }
    ex2 *= invN;
    const float var   = ex2 - mean * mean;
    const float scale = gamma[lane] * rsqrtf(var + BN_EPS);
    const float bias  = fmaf(-mean, scale, beta[lane]);

    // folded weights, scale pre-multiplied
    const float a0 = (w[0] + w[4] + w[7]) * scale;
    const float a1 = (w[1] + w[5] + w[8]) * scale;
    const float a2 = (w[2] + w[6]) * scale;
    const float a3 =  w[3] * scale;
    const float u4 = w[4] * scale, u5 = w[5] * scale, u6 = w[6] * scale;
    const float u7 = w[7] * scale, u8 = w[8] * scale;

    const int gw = (blockIdx.x * 256 + threadIdx.x) >> 6;   // 0..9999

#pragma unroll
    for (int it = 0; it < 4; ++it) {
        const int v = gw * 4 + it;

        float4 q = voxels[(size_t)v * P_N + pl];
        float sx = q.x, sy = q.y, sz = q.z;
#pragma unroll
        for (int m = 1; m < 32; m <<= 1) {
            sx += __shfl_xor(sx, m, 64);
            sy += __shfl_xor(sy, m, 64);
            sz += __shfl_xor(sz, m, 64);
        }
        if (lane < 32) sq[wib][lane] = q;
        __builtin_amdgcn_wave_barrier();

        const int   npts = npts_arr[v];
        const float inv  = 1.f / (float)npts;
        const float mx = sx * inv, my = sy * inv, mz = sz * inv;
        const float cx = (float)coors[2 * v]     * VXc + XOFF;
        const float cy = (float)coors[2 * v + 1] * VYc + YOFF;
        const float b  = -(mx * u4 + my * u5 + mz * u6 + cx * u7 + cy * u8);

        float macc = -3.4e38f;
#pragma unroll
        for (int p = 0; p < P_N; ++p) {
            float4 t = sq[wib][p];                       // broadcast read
            float d = fmaf(t.x, a0, fmaf(t.y, a1, fmaf(t.z, a2, t.w * a3)));
            macc = (p < npts) ? fmaxf(macc, d) : macc;   // uniform select
        }
        float mfin = macc + b;
        if (npts < P_N) mfin = fmaxf(mfin, 0.f);         // masked rows: x=0
        out[(size_t)v * 64 + lane] = fmaxf(mfin + bias, 0.f);
        __builtin_amdgcn_wave_barrier();
    }
}

// ---------------------------------------------------------------------------
extern "C" void kernel_launch(void* const* d_in, const int* in_sizes, int n_in,
                              void* d_out, int out_size, void* d_ws, size_t ws_size,
                              hipStream_t stream)
{
    const float4* voxels = (const float4*)d_in[0];
    const int*    npts   = (const int*)d_in[1];
    const int*    coors  = (const int*)d_in[2];
    const float*  W      = (const float*)d_in[3];
    const float*  gamma  = (const float*)d_in[4];
    const float*  beta   = (const float*)d_in[5];
    float*        out    = (float*)d_out;
    float*        stats  = (float*)d_ws;   // 54 floats

    hipMemsetAsync(stats, 0, 54 * sizeof(float), stream);
    stats_kernel<<<SBLK, 256, 0, stream>>>(voxels, npts, coors, stats);
    pfn_kernel<<<PBLK, 256, 0, stream>>>(voxels, npts, coors, W, gamma, beta,
                                         stats, out);
}

// Round 4
// 125.744 us; speedup vs baseline: 1.3605x; 1.3605x over previous
//
#include <hip/hip_runtime.h>
#include <hip/hip_bf16.h>

#define V_N   40000
#define P_N   32
#define NTOT  (V_N * P_N)            // BN batch positions
#define VXc   0.16f
#define VYc   0.16f
#define XOFF  0.08f                  // VX/2 + 0.0
#define YOFF  (-39.6f)               // VY/2 - 39.68
#define BN_EPS 1e-5f

#define SBLK  625                    // stats blocks: 2500 waves, 8 iters of 2 voxels
#define PBLK  2500                   // pfn blocks: 10000 waves x 4 voxels = 40000

// 54 moment slots as NAMED SCALARS (arrays failed SROA -> scratch -> 250 MB
// of HBM write traffic; named scalars cannot fail promotion).
#define FOR_S(X) X(0) X(1) X(2) X(3) X(4) X(5) X(6) X(7) X(8)
#define FOR_M(X) \
  X(0,0) X(0,1) X(0,2) X(0,3) X(0,4) X(0,5) X(0,6) X(0,7) X(0,8) \
  X(1,1) X(1,2) X(1,3) X(1,4) X(1,5) X(1,6) X(1,7) X(1,8) \
  X(2,2) X(2,3) X(2,4) X(2,5) X(2,6) X(2,7) X(2,8) \
  X(3,3) X(3,4) X(3,5) X(3,6) X(3,7) X(3,8) \
  X(4,4) X(4,5) X(4,6) X(4,7) X(4,8) \
  X(5,5) X(5,6) X(5,7) X(5,8) \
  X(6,6) X(6,7) X(6,8) \
  X(7,7) X(7,8) \
  X(8,8)

__device__ __forceinline__ float wave_sum(float x) {
#pragma unroll
    for (int m = 1; m < 64; m <<= 1) x += __shfl_xor(x, m, 64);
    return x;
}

// ---------------------------------------------------------------------------
// Kernel 1: S = sum f, M = upper-tri sum f f^T over valid (v,p).
// (v,p)-parallel: wave = 2 voxels/iter (lane&31 = point, lane>>5 = voxel).
// Masked points contribute via g=0 multiply (g^2 = g, so moments exact).
// ---------------------------------------------------------------------------
__global__ __launch_bounds__(256) void stats_kernel(
    const float4* __restrict__ voxels,
    const int*    __restrict__ npts_arr,
    const int*    __restrict__ coors,
    float*        __restrict__ stats)       // 54 floats, pre-zeroed
{
    const int lane = threadIdx.x & 63;
    const int p    = lane & 31;
    const int half = lane >> 5;
    const int gw   = (blockIdx.x * 256 + threadIdx.x) >> 6;
    const int nw   = (SBLK * 256) >> 6;     // 2500 waves

#define DECL_S(i)   float S##i = 0.f;
#define DECL_M(i,j) float M##i##_##j = 0.f;
    FOR_S(DECL_S)
    FOR_M(DECL_M)

    for (int vb = gw * 2; vb < V_N; vb += nw * 2) {
        const int v = vb + half;                       // V_N even -> in range
        float4 q = voxels[(size_t)v * P_N + p];

        // per-voxel xyz sum over ALL 32 points (reference does not mask here);
        // masks 1..16 stay within each 32-lane half
        float sx = q.x, sy = q.y, sz = q.z;
#pragma unroll
        for (int m = 1; m < 32; m <<= 1) {
            sx += __shfl_xor(sx, m, 64);
            sy += __shfl_xor(sy, m, 64);
            sz += __shfl_xor(sz, m, 64);
        }
        const int   npts = npts_arr[v];
        const float inv  = 1.f / (float)npts;
        const float cx = (float)coors[2 * v]     * VXc + XOFF;
        const float cy = (float)coors[2 * v + 1] * VYc + YOFF;

        const float g  = (p < npts) ? 1.f : 0.f;
        const float f0 = q.x * g;
        const float f1 = q.y * g;
        const float f2 = q.z * g;
        const float f3 = q.w * g;
        const float f4 = (q.x - sx * inv) * g;
        const float f5 = (q.y - sy * inv) * g;
        const float f6 = (q.z - sz * inv) * g;
        const float f7 = (q.x - cx) * g;
        const float f8 = (q.y - cy) * g;

#define ACC_S(i)   S##i += f##i;
#define ACC_M(i,j) M##i##_##j = fmaf(f##i, f##j, M##i##_##j);
        FOR_S(ACC_S)
        FOR_M(ACC_M)
    }

    // 64-lane butterfly per scalar (sums both halves = both voxel streams)
#define RED_S(i)   S##i = wave_sum(S##i);
#define RED_M(i,j) M##i##_##j = wave_sum(M##i##_##j);
    FOR_S(RED_S)
    FOR_M(RED_M)

    // block-level reduce (4 waves) then 54 parallel-lane atomics per block
    __shared__ float red[4][54];
    const int wib = threadIdx.x >> 6;
    if (lane == 0) {
        float* r = red[wib];
        int k = 0;
#define ST_S(i)   r[k++] = S##i;
#define ST_M(i,j) r[k++] = M##i##_##j;
        FOR_S(ST_S)
        FOR_M(ST_M)
    }
    __syncthreads();
    if (threadIdx.x < 54) {
        float s = red[0][threadIdx.x] + red[1][threadIdx.x]
                + red[2][threadIdx.x] + red[3][threadIdx.x];
        atomicAdd(&stats[threadIdx.x], s);
    }
}

// ---------------------------------------------------------------------------
// Kernel 2: one wave per voxel iter (4 voxels per wave). Lane o = out channel.
// Folded affine: scale*(f_p . w_o) = q_p . a_o + b_{v,o} with a_o per-lane
// constants (scale folded in) and b point-invariant -> added after the max.
// (unchanged this round so its counters surface cleanly)
// ---------------------------------------------------------------------------
__global__ __launch_bounds__(256) void pfn_kernel(
    const float4* __restrict__ voxels,
    const int*    __restrict__ npts_arr,
    const int*    __restrict__ coors,
    const float*  __restrict__ W,        // (64, 9) row-major
    const float*  __restrict__ gamma,
    const float*  __restrict__ beta,
    const float*  __restrict__ stats,    // 54 floats
    float*        __restrict__ out)      // (V, 64)
{
    __shared__ float4 sq[4][P_N];
    const int wib  = threadIdx.x >> 6;
    const int lane = threadIdx.x & 63;
    const int pl   = lane & 31;

    // ---- BN affine from moment statistics (once per wave) ----
    float w[9];
#pragma unroll
    for (int c = 0; c < 9; ++c) w[c] = W[lane * 9 + c];

    const float invN = 1.f / (float)NTOT;
    float mean = 0.f;
#pragma unroll
    for (int c = 0; c < 9; ++c) mean = fmaf(w[c], stats[c], mean);
    mean *= invN;

    float ex2 = 0.f;
    {
        int k = 9;
#pragma unroll
        for (int i = 0; i < 9; ++i)
#pragma unroll
            for (int j = i; j < 9; ++j) {
                const float coef = (i == j) ? 1.f : 2.f;
                ex2 = fmaf(coef * w[i] * w[j], stats[k], ex2);
                ++k;
            }
    }
    ex2 *= invN;
    const float var   = ex2 - mean * mean;
    const float scale = gamma[lane] * rsqrtf(var + BN_EPS);
    const float bias  = fmaf(-mean, scale, beta[lane]);

    // folded weights, scale pre-multiplied
    const float a0 = (w[0] + w[4] + w[7]) * scale;
    const float a1 = (w[1] + w[5] + w[8]) * scale;
    const float a2 = (w[2] + w[6]) * scale;
    const float a3 =  w[3] * scale;
    const float u4 = w[4] * scale, u5 = w[5] * scale, u6 = w[6] * scale;
    const float u7 = w[7] * scale, u8 = w[8] * scale;

    const int gw = (blockIdx.x * 256 + threadIdx.x) >> 6;   // 0..9999

#pragma unroll
    for (int it = 0; it < 4; ++it) {
        const int v = gw * 4 + it;

        float4 q = voxels[(size_t)v * P_N + pl];
        float sx = q.x, sy = q.y, sz = q.z;
#pragma unroll
        for (int m = 1; m < 32; m <<= 1) {
            sx += __shfl_xor(sx, m, 64);
            sy += __shfl_xor(sy, m, 64);
            sz += __shfl_xor(sz, m, 64);
        }
        if (lane < 32) sq[wib][lane] = q;
        __builtin_amdgcn_wave_barrier();

        const int   npts = npts_arr[v];
        const float inv  = 1.f / (float)npts;
        const float mx = sx * inv, my = sy * inv, mz = sz * inv;
        const float cx = (float)coors[2 * v]     * VXc + XOFF;
        const float cy = (float)coors[2 * v + 1] * VYc + YOFF;
        const float b  = -(mx * u4 + my * u5 + mz * u6 + cx * u7 + cy * u8);

        float macc = -3.4e38f;
#pragma unroll
        for (int p = 0; p < P_N; ++p) {
            float4 t = sq[wib][p];                       // broadcast read
            float d = fmaf(t.x, a0, fmaf(t.y, a1, fmaf(t.z, a2, t.w * a3)));
            macc = (p < npts) ? fmaxf(macc, d) : macc;   // uniform select
        }
        float mfin = macc + b;
        if (npts < P_N) mfin = fmaxf(mfin, 0.f);         // masked rows: x=0
        out[(size_t)v * 64 + lane] = fmaxf(mfin + bias, 0.f);
        __builtin_amdgcn_wave_barrier();
    }
}

// ---------------------------------------------------------------------------
extern "C" void kernel_launch(void* const* d_in, const int* in_sizes, int n_in,
                              void* d_out, int out_size, void* d_ws, size_t ws_size,
                              hipStream_t stream)
{
    const float4* voxels = (const float4*)d_in[0];
    const int*    npts   = (const int*)d_in[1];
    const int*    coors  = (const int*)d_in[2];
    const float*  W      = (const float*)d_in[3];
    const float*  gamma  = (const float*)d_in[4];
    const float*  beta   = (const float*)d_in[5];
    float*        out    = (float*)d_out;
    float*        stats  = (float*)d_ws;   // 54 floats

    hipMemsetAsync(stats, 0, 54 * sizeof(float), stream);
    stats_kernel<<<SBLK, 256, 0, stream>>>(voxels, npts, coors, stats);
    pfn_kernel<<<PBLK, 256, 0, stream>>>(voxels, npts, coors, W, gamma, beta,
                                         stats, out);
}